// Round 1
// baseline (38.268 us; speedup 1.0000x reference)
//
#include <hip/hip_runtime.h>

#define FN 50
#define CARD 10000
#define NP 1225      // F*(F-1)/2
#define NTILE 77     // ceil(NP/16)
#define NPAD (NTILE*16)  // 1232

typedef _Float16 half8 __attribute__((ext_vector_type(8)));
typedef _Float16 half2t __attribute__((ext_vector_type(2)));
typedef float floatx4 __attribute__((ext_vector_type(4)));

__global__ __launch_bounds__(256, 4)
void afm_kernel(const int* __restrict__ inp,
                const float* __restrict__ emb,
                const float* __restrict__ wlin,
                const float* __restrict__ blin,
                const float* __restrict__ W1,
                const float* __restrict__ b1,
                const float* __restrict__ W2,
                const float* __restrict__ b2,
                float* __restrict__ out)
{
  __shared__ __align__(16) _Float16 s_fac[FN][72];   // padded: 144B row stride
  __shared__ unsigned char s_iu[NPAD], s_ju[NPAD];
  __shared__ float s_logit[NPAD], s_pool[NPAD];
  __shared__ float s_wl[FN];
  __shared__ float s_red[16];

  const int tid  = threadIdx.x;
  const int b    = blockIdx.x;
  const int lane = tid & 63;
  const int wave = tid >> 6;
  const int c    = lane & 15;   // column-in-fragment
  const int kq   = lane >> 4;   // k-group 0..3

  // ---- phase 0: pair tables, factor gather (f32 -> f16 LDS), per-lane W1 frags ----
  for (int p = tid; p < NPAD; p += 256) {
    int pp = p < NP ? p : NP - 1;
    int i = 0;
    // off(i) = i*(99-i)/2 ; advance while off(i+1) <= pp
    while ((i + 1) * (98 - i) / 2 <= pp) ++i;
    int j = pp - i * (99 - i) / 2 + i + 1;
    s_iu[p] = (unsigned char)i;
    s_ju[p] = (unsigned char)j;
  }
  const int* inprow = inp + b * FN;
  for (int idx = tid; idx < FN * 16; idx += 256) {
    int f = idx >> 4, q = idx & 15;
    long flat = (long)inprow[f] + f * CARD;
    floatx4 v = ((const floatx4*)emb)[flat * 16 + q];
    _Float16* dst = &s_fac[f][q * 4];
    dst[0] = (_Float16)v[0]; dst[1] = (_Float16)v[1];
    dst[2] = (_Float16)v[2]; dst[3] = (_Float16)v[3];
  }
  if (tid < FN) {
    int flat = inprow[tid] + tid * CARD;
    s_wl[tid] = wlin[flat];
  }
  // B-fragments of W1 (K x N layout: n = lane&15, k = (lane>>4)*8 + j)
  half8 w1f[2][4];
  float myb1[4], myw2[4];
#pragma unroll
  for (int nt = 0; nt < 4; ++nt) {
    myb1[nt] = b1[nt * 16 + c];
    myw2[nt] = W2[nt * 16 + c];
  }
#pragma unroll
  for (int ks = 0; ks < 2; ++ks)
#pragma unroll
    for (int nt = 0; nt < 4; ++nt)
#pragma unroll
      for (int j = 0; j < 8; ++j)
        w1f[ks][nt][j] = (_Float16)W1[(ks * 32 + kq * 8 + j) * 64 + nt * 16 + c];

  __syncthreads();

  // ---- phase 1: pair tiles of 16, MFMA h = relu(inter @ W1), logit = h . W2 ----
  for (int t = wave; t < NTILE; t += 4) {
    int pA = t * 16 + c;            // A-row pair for this lane
    int ia = s_iu[pA], ja = s_ju[pA];
    floatx4 acc[4] = {floatx4{0,0,0,0}, floatx4{0,0,0,0},
                      floatx4{0,0,0,0}, floatx4{0,0,0,0}};
    float pool = 0.f;
#pragma unroll
    for (int ks = 0; ks < 2; ++ks) {
      half8 vi = *(const half8*)&s_fac[ia][ks * 32 + kq * 8];
      half8 vj = *(const half8*)&s_fac[ja][ks * 32 + kq * 8];
      half8 prod = vi * vj;         // inter = f_i * f_j, elementwise f16
#pragma unroll
      for (int q = 0; q < 4; ++q) {
        half2t a2 = { vi[2*q], vi[2*q+1] };
        half2t b2v = { vj[2*q], vj[2*q+1] };
#if __has_builtin(__builtin_amdgcn_fdot2)
        pool = __builtin_amdgcn_fdot2(a2, b2v, pool, false);
#else
        pool += (float)a2[0]*(float)b2v[0] + (float)a2[1]*(float)b2v[1];
#endif
      }
#pragma unroll
      for (int nt = 0; nt < 4; ++nt)
        acc[nt] = __builtin_amdgcn_mfma_f32_16x16x32_f16(prod, w1f[ks][nt], acc[nt], 0, 0, 0);
    }
    // epilogue: relu + dot(W2) in D-fragment layout (col=lane&15, row=(lane>>4)*4+r)
    float part[4] = {0.f, 0.f, 0.f, 0.f};
#pragma unroll
    for (int nt = 0; nt < 4; ++nt) {
#pragma unroll
      for (int r = 0; r < 4; ++r) {
        float h = acc[nt][r] + myb1[nt];
        h = fmaxf(h, 0.f);
        part[r] = fmaf(h, myw2[nt], part[r]);
      }
    }
#pragma unroll
    for (int msk = 1; msk <= 8; msk <<= 1) {
#pragma unroll
      for (int r = 0; r < 4; ++r)
        part[r] += __shfl_xor(part[r], msk, 64);
    }
    pool += __shfl_xor(pool, 16, 64);
    pool += __shfl_xor(pool, 32, 64);
    if (c < 4) {
      int pD = t * 16 + kq * 4 + c;
      float v = (c == 0) ? part[0] : (c == 1) ? part[1] : (c == 2) ? part[2] : part[3];
      if (pD < NP) s_logit[pD] = v;   // b2 omitted: softmax-invariant
    }
    if (lane < 16) {
      int p = t * 16 + lane;
      if (p < NP) s_pool[p] = pool;
    }
  }

  __syncthreads();

  // ---- phase 2: softmax over pairs + weighted pooled sum + line_out ----
  float m = -1e30f;
  for (int p = tid; p < NP; p += 256) m = fmaxf(m, s_logit[p]);
#pragma unroll
  for (int o = 32; o; o >>= 1) m = fmaxf(m, __shfl_xor(m, o, 64));
  if (lane == 0) s_red[wave] = m;
  __syncthreads();
  m = fmaxf(fmaxf(s_red[0], s_red[1]), fmaxf(s_red[2], s_red[3]));
  float se = 0.f, spe = 0.f;
  for (int p = tid; p < NP; p += 256) {
    float e = __expf(s_logit[p] - m);
    se += e;
    spe += e * s_pool[p];
  }
#pragma unroll
  for (int o = 32; o; o >>= 1) {
    se  += __shfl_xor(se, o, 64);
    spe += __shfl_xor(spe, o, 64);
  }
  if (lane == 0) { s_red[4 + wave] = se; s_red[8 + wave] = spe; }
  __syncthreads();
  if (tid == 0) {
    float line = blin[0];
#pragma unroll
    for (int f = 0; f < FN; ++f) line += s_wl[f];
    float SE  = s_red[4] + s_red[5] + s_red[6]  + s_red[7];
    float SPE = s_red[8] + s_red[9] + s_red[10] + s_red[11];
    out[b] = line + SPE / SE;
  }
}

extern "C" void kernel_launch(void* const* d_in, const int* in_sizes, int n_in,
                              void* d_out, int out_size, void* d_ws, size_t ws_size,
                              hipStream_t stream) {
  const int*   inp  = (const int*)d_in[0];
  const float* emb  = (const float*)d_in[1];
  const float* wlin = (const float*)d_in[2];
  const float* blin = (const float*)d_in[3];
  const float* W1   = (const float*)d_in[4];
  const float* b1   = (const float*)d_in[5];
  const float* W2   = (const float*)d_in[6];
  const float* b2   = (const float*)d_in[7];
  float* outp = (float*)d_out;
  const int B = in_sizes[0] / FN;
  afm_kernel<<<B, 256, 0, stream>>>(inp, emb, wlin, blin, W1, b1, W2, b2, outp);
}

// Round 3
// 26.563 us; speedup vs baseline: 1.4406x; 1.4406x over previous
//
#include <hip/hip_runtime.h>
#include <math.h>

#define FN 50
#define CARD 10000
#define NP 1225          // F*(F-1)/2
#define NTILE 77         // ceil(NP/16)
#define NPAD (NTILE*16)  // 1232
#define FSTRIDE 72       // halves per factor row (144 B, breaks pow2 bank stride)

typedef _Float16 half8 __attribute__((ext_vector_type(8)));
typedef __fp16 half2t __attribute__((ext_vector_type(2)));
typedef float floatx4 __attribute__((ext_vector_type(4)));

static __device__ __forceinline__ half2t h2max0(half2t v) {
  half2t r;
  r[0] = v[0] > (__fp16)0 ? v[0] : (__fp16)0;
  r[1] = v[1] > (__fp16)0 ? v[1] : (__fp16)0;
  return r;
}

static __device__ __forceinline__ float hdot2(half2t a, half2t b, float c) {
#if __has_builtin(__builtin_amdgcn_fdot2)
  return __builtin_amdgcn_fdot2(a, b, c, false);
#else
  return c + (float)a[0]*(float)b[0] + (float)a[1]*(float)b[1];
#endif
}

__global__ __launch_bounds__(256, 4)
void afm_kernel(const int* __restrict__ inp,
                const float* __restrict__ emb,
                const float* __restrict__ wlin,
                const float* __restrict__ blin,
                const float* __restrict__ W1,
                const float* __restrict__ b1,
                const float* __restrict__ W2,
                const float* __restrict__ b2,
                float* __restrict__ out)
{
  __shared__ __align__(16) _Float16 s_fac[FN][FSTRIDE];
  __shared__ unsigned int s_pij[NPAD];      // packed byte offsets: lo16 = i*144, hi16 = j*144
  __shared__ float s_logit[NPAD], s_pool[NPAD];
  __shared__ float s_wl[FN];
  __shared__ float s_red[16];

  const int tid  = threadIdx.x;
  const int b    = blockIdx.x;
  const int lane = tid & 63;
  const int wave = tid >> 6;
  const int c    = lane & 15;   // fragment row/col index
  const int kq   = lane >> 4;   // k-quarter 0..3

  // ---- phase 0a: pair table, closed form (no per-block O(F*P) loop) ----
  for (int p = tid; p < NPAD; p += 256) {
    int pp = p < NP ? p : NP - 1;
    int i = (int)((99.0f - sqrtf(9801.0f - 8.0f * (float)pp)) * 0.5f);
    if (i < 0) i = 0;
    while ((i + 1) * (98 - i) / 2 <= pp) ++i;      // off(i+1) <= pp -> advance
    while (i > 0 && i * (99 - i) / 2 > pp) --i;    // overshoot fixup
    int j = pp - i * (99 - i) / 2 + i + 1;
    s_pij[p] = (unsigned)(i * (FSTRIDE * 2)) | ((unsigned)(j * (FSTRIDE * 2)) << 16);
  }

  // ---- phase 0b: factor gather f32 -> f16 LDS ----
  const int* inprow = inp + b * FN;
  for (int idx = tid; idx < FN * 16; idx += 256) {
    int f = idx >> 4, q = idx & 15;
    long flat = (long)inprow[f] + f * CARD;
    floatx4 v = ((const floatx4*)emb)[flat * 16 + q];
    _Float16* dst = &s_fac[f][q * 4];
    dst[0] = (_Float16)v[0]; dst[1] = (_Float16)v[1];
    dst[2] = (_Float16)v[2]; dst[3] = (_Float16)v[3];
  }
  if (tid < FN) {
    int flat = inprow[tid] + tid * CARD;
    s_wl[tid] = wlin[flat];
  }

  // ---- phase 0c: per-lane fragments (swapped orientation: A = W1^T chunk) ----
  // A[m=a][k=d]: a = mt*16 + c, d = ks*32 + kq*8 + j  ->  W1[d*64 + a]
  half8 w1f[2][4];
#pragma unroll
  for (int ks = 0; ks < 2; ++ks)
#pragma unroll
    for (int mt = 0; mt < 4; ++mt)
#pragma unroll
      for (int jj = 0; jj < 4; ++jj) {
        float x = W1[(ks * 32 + kq * 8 + 2 * jj)     * 64 + mt * 16 + c];
        float y = W1[(ks * 32 + kq * 8 + 2 * jj + 1) * 64 + mt * 16 + c];
        half2t hw = __builtin_amdgcn_cvt_pkrtz(x, y);
        w1f[ks][mt][2 * jj]     = (_Float16)hw[0];
        w1f[ks][mt][2 * jj + 1] = (_Float16)hw[1];
      }
  // b1 / W2 slices for this lane's 16 a-values (a = mt*16 + kq*4 + r), f16-packed
  half2t b1h[4][2], w2h[4][2];
#pragma unroll
  for (int mt = 0; mt < 4; ++mt) {
    floatx4 bv = ((const floatx4*)b1)[mt * 4 + kq];
    floatx4 wv = ((const floatx4*)W2)[mt * 4 + kq];
    b1h[mt][0] = __builtin_amdgcn_cvt_pkrtz(bv[0], bv[1]);
    b1h[mt][1] = __builtin_amdgcn_cvt_pkrtz(bv[2], bv[3]);
    w2h[mt][0] = __builtin_amdgcn_cvt_pkrtz(wv[0], wv[1]);
    w2h[mt][1] = __builtin_amdgcn_cvt_pkrtz(wv[2], wv[3]);
  }
  // all-ones A-row (m'=0 of the 5th M-tile) -> pooled[p] = sum_d inter[p][d]
  _Float16 onev = (c == 0) ? (_Float16)1 : (_Float16)0;
  half8 onesf = {onev, onev, onev, onev, onev, onev, onev, onev};

  __syncthreads();

  // ---- phase 1: per 16-pair tile: h^T = W1^T · inter^T (MFMA), fused epilogue ----
  const char* fbase = (const char*)&s_fac[0][0];
  const int koff = kq * 16;   // byte offset of this lane's k-slice within a row
  for (int t = wave; t < NTILE; t += 4) {
    int p = t * 16 + c;               // this lane's pair (B-fragment column)
    unsigned po = s_pij[p];
    int offi = (int)(po & 0xffffu) + koff;
    int offj = (int)(po >> 16) + koff;
    half8 vi0 = *(const half8*)(fbase + offi);
    half8 vj0 = *(const half8*)(fbase + offj);
    half8 vi1 = *(const half8*)(fbase + offi + 64);
    half8 vj1 = *(const half8*)(fbase + offj + 64);
    half8 pr0 = vi0 * vj0;            // inter = f_i ⊙ f_j  (B-frag, k-slice 0)
    half8 pr1 = vi1 * vj1;            // k-slice 1
    floatx4 acc[5];
#pragma unroll
    for (int mt = 0; mt < 5; ++mt) acc[mt] = floatx4{0.f, 0.f, 0.f, 0.f};
#pragma unroll
    for (int mt = 0; mt < 4; ++mt) {
      acc[mt] = __builtin_amdgcn_mfma_f32_16x16x32_f16(w1f[0][mt], pr0, acc[mt], 0, 0, 0);
      acc[mt] = __builtin_amdgcn_mfma_f32_16x16x32_f16(w1f[1][mt], pr1, acc[mt], 0, 0, 0);
    }
    acc[4] = __builtin_amdgcn_mfma_f32_16x16x32_f16(onesf, pr0, acc[4], 0, 0, 0);
    acc[4] = __builtin_amdgcn_mfma_f32_16x16x32_f16(onesf, pr1, acc[4], 0, 0, 0);

    // epilogue: lane holds h[a][p=c] for a = mt*16 + kq*4 + r
    float lg = 0.f;
#pragma unroll
    for (int mt = 0; mt < 4; ++mt) {
      half2t h0 = __builtin_amdgcn_cvt_pkrtz(acc[mt][0], acc[mt][1]);
      half2t h1 = __builtin_amdgcn_cvt_pkrtz(acc[mt][2], acc[mt][3]);
      h0 = h2max0(h0 + b1h[mt][0]);
      h1 = h2max0(h1 + b1h[mt][1]);
      lg = hdot2(h0, w2h[mt][0], lg);
      lg = hdot2(h1, w2h[mt][1], lg);
    }
    lg += __shfl_xor(lg, 16, 64);     // reduce over the 4 k-quarters
    lg += __shfl_xor(lg, 32, 64);
    if (lane < 16 && p < NP) {
      s_logit[p] = lg;                // b2 omitted: softmax-invariant
      s_pool[p]  = acc[4][0];         // row m'=0 of ones-tile = pooled[p]
    }
  }

  __syncthreads();

  // ---- phase 2: softmax over pairs + weighted pooled sum + line_out ----
  float m = -1e30f;
  for (int p = tid; p < NP; p += 256) m = fmaxf(m, s_logit[p]);
#pragma unroll
  for (int o = 32; o; o >>= 1) m = fmaxf(m, __shfl_xor(m, o, 64));
  if (lane == 0) s_red[wave] = m;
  __syncthreads();
  m = fmaxf(fmaxf(s_red[0], s_red[1]), fmaxf(s_red[2], s_red[3]));
  float se = 0.f, spe = 0.f;
  for (int p = tid; p < NP; p += 256) {
    float e = __expf(s_logit[p] - m);
    se += e;
    spe += e * s_pool[p];
  }
#pragma unroll
  for (int o = 32; o; o >>= 1) {
    se  += __shfl_xor(se, o, 64);
    spe += __shfl_xor(spe, o, 64);
  }
  if (lane == 0) { s_red[4 + wave] = se; s_red[8 + wave] = spe; }
  __syncthreads();
  if (tid == 0) {
    float line = blin[0];
#pragma unroll
    for (int f = 0; f < FN; ++f) line += s_wl[f];
    float SE  = s_red[4] + s_red[5] + s_red[6]  + s_red[7];
    float SPE = s_red[8] + s_red[9] + s_red[10] + s_red[11];
    out[b] = line + SPE / SE;
  }
}

extern "C" void kernel_launch(void* const* d_in, const int* in_sizes, int n_in,
                              void* d_out, int out_size, void* d_ws, size_t ws_size,
                              hipStream_t stream) {
  const int*   inp  = (const int*)d_in[0];
  const float* emb  = (const float*)d_in[1];
  const float* wlin = (const float*)d_in[2];
  const float* blin = (const float*)d_in[3];
  const float* W1   = (const float*)d_in[4];
  const float* b1   = (const float*)d_in[5];
  const float* W2   = (const float*)d_in[6];
  const float* b2   = (const float*)d_in[7];
  float* outp = (float*)d_out;
  const int B = in_sizes[0] / FN;
  afm_kernel<<<B, 256, 0, stream>>>(inp, emb, wlin, blin, W1, b1, W2, b2, outp);
}

// Round 4
// 24.813 us; speedup vs baseline: 1.5422x; 1.0705x over previous
//
#include <hip/hip_runtime.h>
#include <math.h>

#define FN 50
#define CARD 10000
#define NP 1225          // F*(F-1)/2
#define NTILE 77         // ceil(NP/16)
#define NPAD (NTILE*16)  // 1232
#define FSTRIDE 72       // halves per factor row (144 B)

typedef _Float16 half8 __attribute__((ext_vector_type(8)));
typedef __fp16 half2t __attribute__((ext_vector_type(2)));
typedef float floatx4 __attribute__((ext_vector_type(4)));

static __device__ __forceinline__ half2t h2max0(half2t v) {
  half2t r;
  r[0] = v[0] > (__fp16)0 ? v[0] : (__fp16)0;
  r[1] = v[1] > (__fp16)0 ? v[1] : (__fp16)0;
  return r;
}
static __device__ __forceinline__ float hdot2(half2t a, half2t b, float c) {
#if __has_builtin(__builtin_amdgcn_fdot2)
  return __builtin_amdgcn_fdot2(a, b, c, false);
#else
  return c + (float)a[0]*(float)b[0] + (float)a[1]*(float)b[1];
#endif
}

__global__ __launch_bounds__(256, 4)
void afm_kernel(const int* __restrict__ inp,
                const float* __restrict__ emb,
                const float* __restrict__ wlin,
                const float* __restrict__ blin,
                const float* __restrict__ W1,
                const float* __restrict__ b1,
                const float* __restrict__ W2,
                const float* __restrict__ b2,
                float* __restrict__ out)
{
  __shared__ __align__(16) _Float16 s_fac[FN][FSTRIDE];   // 7200 B
  __shared__ __align__(16) _Float16 s_w1[512 * 8];        // 8192 B, frag layout
  __shared__ __align__(16) unsigned s_pij[NPAD];          // 4928 B (aliased to f32 logits in phase 2)
  __shared__ __align__(16) __fp16 s_lg4[NPAD * 4];        // 9856 B, per-kq logit partials
  __shared__ float s_pool[NPAD];                          // 4928 B
  __shared__ float s_wl[FN];
  __shared__ float s_red[16];

  const int tid  = threadIdx.x;
  const int b    = blockIdx.x;
  const int lane = tid & 63;
  const int wave = tid >> 6;
  const int c    = lane & 15;   // fragment row/col index
  const int kq   = lane >> 4;   // k-quarter 0..3

  // ---- phase 0a: pair table (closed form) ----
  for (int p = tid; p < NPAD; p += 256) {
    int pp = p < NP ? p : NP - 1;
    int i = (int)((99.0f - sqrtf(9801.0f - 8.0f * (float)pp)) * 0.5f);
    if (i < 0) i = 0;
    while ((i + 1) * (98 - i) / 2 <= pp) ++i;
    while (i > 0 && i * (99 - i) / 2 > pp) --i;
    int j = pp - i * (99 - i) / 2 + i + 1;
    s_pij[p] = (unsigned)(i * (FSTRIDE * 2)) | ((unsigned)(j * (FSTRIDE * 2)) << 16);
  }

  // ---- phase 0b: factor gather f32 -> f16 LDS ----
  const int* inprow = inp + b * FN;
  for (int idx = tid; idx < FN * 16; idx += 256) {
    int f = idx >> 4, q = idx & 15;
    int flat = inprow[f] + f * CARD;
    floatx4 v = ((const floatx4*)emb)[(long)flat * 16 + q];
    _Float16* dst = &s_fac[f][q * 4];
    dst[0] = (_Float16)v[0]; dst[1] = (_Float16)v[1];
    dst[2] = (_Float16)v[2]; dst[3] = (_Float16)v[3];
  }
  if (tid < FN) {
    int flat = inprow[tid] + tid * CARD;
    s_wl[tid] = wlin[flat];
  }

  // ---- phase 0c: stage W1 into LDS in fragment layout ----
  // chunk ch = ks*256 + mt*64 + ln ; holds halves j=0..7 of A[m=mt*16+cc][k=ks*32+kk*8+j]
  for (int ch = tid; ch < 512; ch += 256) {
    int ks = ch >> 8, mt = (ch >> 6) & 3, ln = ch & 63;
    int cc = ln & 15, kk = ln >> 4;
    _Float16 tmp[8];
#pragma unroll
    for (int j = 0; j < 8; ++j)
      tmp[j] = (_Float16)W1[(ks * 32 + kk * 8 + j) * 64 + mt * 16 + cc];
    *(half8*)&s_w1[ch * 8] = *(const half8*)tmp;
  }

  // per-lane bias (f32, used as MFMA C-in) and W2 slice (f16 packed)
  floatx4 bias[4];
  half2t w2h[4][2];
#pragma unroll
  for (int mt = 0; mt < 4; ++mt) {
    bias[mt] = ((const floatx4*)b1)[mt * 4 + kq];
    floatx4 wv = ((const floatx4*)W2)[mt * 4 + kq];
    w2h[mt][0] = __builtin_amdgcn_cvt_pkrtz(wv[0], wv[1]);
    w2h[mt][1] = __builtin_amdgcn_cvt_pkrtz(wv[2], wv[3]);
  }
  _Float16 onev = (c == 0) ? (_Float16)1 : (_Float16)0;
  half8 onesf = {onev, onev, onev, onev, onev, onev, onev, onev};

  __syncthreads();

  // ---- phase 1: pipelined pair tiles ----
#define LDW1(ks, mt) (*(const half8*)&s_w1[(((ks) * 4 + (mt)) * 64 + lane) * 8])
  const char* fbase = (const char*)&s_fac[0][0];
  const int koff = kq * 16;

  int t = wave;
  int pcur = t * 16 + c;
  unsigned po = s_pij[pcur];
  int offi = (int)(po & 0xffffu) + koff;
  int offj = (int)(po >> 16) + koff;
  half8 cvi0 = *(const half8*)(fbase + offi);
  half8 cvj0 = *(const half8*)(fbase + offj);
  half8 cvi1 = *(const half8*)(fbase + offi + 64);
  half8 cvj1 = *(const half8*)(fbase + offj + 64);

  while (true) {
    int tn = t + 4;
    int pn = tn * 16 + c; if (pn > NPAD - 1) pn = NPAD - 1;
    unsigned pon = s_pij[pn];                 // prefetch pij (next)

    half8 pr0 = cvi0 * cvj0;                  // inter, k-slice 0
    half8 pr1 = cvi1 * cvj1;                  // k-slice 1

    floatx4 acc[4];
#pragma unroll
    for (int mt = 0; mt < 4; ++mt) {
      acc[mt] = __builtin_amdgcn_mfma_f32_16x16x32_f16(LDW1(0, mt), pr0, bias[mt], 0, 0, 0);
      acc[mt] = __builtin_amdgcn_mfma_f32_16x16x32_f16(LDW1(1, mt), pr1, acc[mt], 0, 0, 0);
    }
    floatx4 accp = __builtin_amdgcn_mfma_f32_16x16x32_f16(onesf, pr0, (floatx4){0.f,0.f,0.f,0.f}, 0, 0, 0);
    accp = __builtin_amdgcn_mfma_f32_16x16x32_f16(onesf, pr1, accp, 0, 0, 0);

    // prefetch next tile's fragments under the epilogue
    int offi_n = (int)(pon & 0xffffu) + koff;
    int offj_n = (int)(pon >> 16) + koff;
    cvi0 = *(const half8*)(fbase + offi_n);
    cvj0 = *(const half8*)(fbase + offj_n);
    cvi1 = *(const half8*)(fbase + offi_n + 64);
    cvj1 = *(const half8*)(fbase + offj_n + 64);

    // epilogue: relu (bias already in acc) + W2 dot, f16-packed; no cross-lane
    float lg = 0.f;
#pragma unroll
    for (int mt = 0; mt < 4; ++mt) {
      half2t h0 = __builtin_amdgcn_cvt_pkrtz(acc[mt][0], acc[mt][1]);
      half2t h1 = __builtin_amdgcn_cvt_pkrtz(acc[mt][2], acc[mt][3]);
      h0 = h2max0(h0);
      h1 = h2max0(h1);
      lg = hdot2(h0, w2h[mt][0], lg);
      lg = hdot2(h1, w2h[mt][1], lg);
    }
    s_lg4[pcur * 4 + kq] = (__fp16)lg;        // per-kq partial
    if (kq == 0) s_pool[pcur] = accp[0];      // full pooled sum (MFMA reduced k)

    t = tn;
    if (t >= NTILE) break;
    pcur = t * 16 + c;
  }
#undef LDW1

  __syncthreads();

  // ---- phase 2: sum partials, softmax, weighted pool, line_out ----
  float* s_logit = (float*)s_pij;             // alias: pij dead now
  float m = -1e30f;
  for (int p = tid; p < NP; p += 256) {
    const half2t* lp = (const half2t*)&s_lg4[p * 4];
    half2t sfh = lp[0] + lp[1];
    float lg = (float)sfh[0] + (float)sfh[1];
    s_logit[p] = lg;
    m = fmaxf(m, lg);
  }
#pragma unroll
  for (int o = 32; o; o >>= 1) m = fmaxf(m, __shfl_xor(m, o, 64));
  if (lane == 0) s_red[wave] = m;
  __syncthreads();
  m = fmaxf(fmaxf(s_red[0], s_red[1]), fmaxf(s_red[2], s_red[3]));
  float se = 0.f, spe = 0.f;
  for (int p = tid; p < NP; p += 256) {
    float e = __expf(s_logit[p] - m);
    se += e;
    spe += e * s_pool[p];
  }
#pragma unroll
  for (int o = 32; o; o >>= 1) {
    se  += __shfl_xor(se, o, 64);
    spe += __shfl_xor(spe, o, 64);
  }
  if (lane == 0) { s_red[4 + wave] = se; s_red[8 + wave] = spe; }
  __syncthreads();
  if (tid == 0) {
    float line = blin[0];
#pragma unroll
    for (int f = 0; f < FN; ++f) line += s_wl[f];
    float SE  = s_red[4] + s_red[5] + s_red[6]  + s_red[7];
    float SPE = s_red[8] + s_red[9] + s_red[10] + s_red[11];
    out[b] = line + SPE / SE;
  }
}

extern "C" void kernel_launch(void* const* d_in, const int* in_sizes, int n_in,
                              void* d_out, int out_size, void* d_ws, size_t ws_size,
                              hipStream_t stream) {
  const int*   inp  = (const int*)d_in[0];
  const float* emb  = (const float*)d_in[1];
  const float* wlin = (const float*)d_in[2];
  const float* blin = (const float*)d_in[3];
  const float* W1   = (const float*)d_in[4];
  const float* b1   = (const float*)d_in[5];
  const float* W2   = (const float*)d_in[6];
  const float* b2   = (const float*)d_in[7];
  float* outp = (float*)d_out;
  const int B = in_sizes[0] / FN;
  afm_kernel<<<B, 256, 0, stream>>>(inp, emb, wlin, blin, W1, b1, W2, b2, outp);
}